// Round 7
// baseline (359.701 us; speedup 1.0000x reference)
//
#include <hip/hip_runtime.h>
#include <hip/hip_bf16.h>
#include <cstdint>

#define T_TOK 2048
#define D_DIM 1024
#define E_NUM 16
#define K_TOP 4
#define I_DIM 512
#define TWOI  1024

typedef __bf16 bf16x8 __attribute__((ext_vector_type(8)));
typedef __bf16 bf16x4 __attribute__((ext_vector_type(4)));
typedef float  f32x4  __attribute__((ext_vector_type(4)));

__device__ __forceinline__ void gload_lds16(const void* g, void* l) {
    __builtin_amdgcn_global_load_lds(
        (const __attribute__((address_space(1))) void*)(uintptr_t)(g),
        (__attribute__((address_space(3))) void*)(uintptr_t)(l),
        16, 0, 0);
}

// ---------------- router: wave-per-token, fp32 exact, [d][e] layout ----------
// Lane l covers d in [16l,16l+16): per-lane contiguous x (4 float4) and
// contiguous router rows (16x 64B). acc[16] per lane, LDS column reduction.
__global__ __launch_bounds__(256) void router_wave2_kernel(
    const float* __restrict__ x, const float* __restrict__ router,
    const float* __restrict__ rbias,
    int* __restrict__ sel_idx, float* __restrict__ sel_w, int* __restrict__ counts)
{
    __shared__ float red[4][64][20];   // [wave][lane][16 experts], pad 20 for banks
    const int wv = threadIdx.x >> 6, lane = threadIdx.x & 63;
    const int t = blockIdx.x * 4 + wv;

    const float* xr = x + (size_t)t * D_DIM + lane * 16;
    f32x4 xv[4];
#pragma unroll
    for (int c = 0; c < 4; ++c) xv[c] = *reinterpret_cast<const f32x4*>(xr + c * 4);

    const float* rb = router + (size_t)(lane * 16) * E_NUM;
    float acc[E_NUM];
#pragma unroll
    for (int e = 0; e < E_NUM; ++e) acc[e] = 0.f;

#pragma unroll
    for (int j = 0; j < 16; ++j) {
        const float xs = xv[j >> 2][j & 3];
        const float* rr = rb + j * E_NUM;
        f32x4 r0 = *reinterpret_cast<const f32x4*>(rr + 0);
        f32x4 r1 = *reinterpret_cast<const f32x4*>(rr + 4);
        f32x4 r2 = *reinterpret_cast<const f32x4*>(rr + 8);
        f32x4 r3 = *reinterpret_cast<const f32x4*>(rr + 12);
#pragma unroll
        for (int c = 0; c < 4; ++c) {
            acc[0 + c]  += xs * r0[c];
            acc[4 + c]  += xs * r1[c];
            acc[8 + c]  += xs * r2[c];
            acc[12 + c] += xs * r3[c];
        }
    }

#pragma unroll
    for (int c = 0; c < 4; ++c) {
        f32x4 v; v[0] = acc[c*4]; v[1] = acc[c*4+1]; v[2] = acc[c*4+2]; v[3] = acc[c*4+3];
        *reinterpret_cast<f32x4*>(&red[wv][lane][c * 4]) = v;
    }
    __syncthreads();

    // column reduction: lane j sums rows g*16.. for expert e=j&15 (g staggered)
    const int e = lane & 15, g = lane >> 4;
    float val = 0.f;
#pragma unroll
    for (int r = 0; r < 16; ++r) {
        const int row = g * 16 + ((r + g * 4) & 15);
        val += red[wv][row][e];
    }
    val += __shfl_xor(val, 16);
    val += __shfl_xor(val, 32);   // all lanes: full logit for expert e=lane&15

    float lg[E_NUM], bi[E_NUM];
#pragma unroll
    for (int j = 0; j < E_NUM; ++j) {
        lg[j] = __shfl(val, j);
        bi[j] = lg[j] + rbias[j];
    }
    if (lane == 0) {
        bool used[E_NUM];
#pragma unroll
        for (int j = 0; j < E_NUM; ++j) used[j] = false;
        int selv[K_TOP]; float wvv[K_TOP]; float wsum = 0.f;
#pragma unroll
        for (int k = 0; k < K_TOP; ++k) {
            float best = -1e30f; int bidx = 0;
#pragma unroll
            for (int j = 0; j < E_NUM; ++j)
                if (!used[j] && bi[j] > best) { best = bi[j]; bidx = j; }
            used[bidx] = true; selv[k] = bidx;
            const float s = 1.f / (1.f + expf(-lg[bidx]));
            wvv[k] = s; wsum += s;
        }
#pragma unroll
        for (int k = 0; k < K_TOP; ++k) {
            sel_idx[t * K_TOP + k] = selv[k];
            sel_w[t * K_TOP + k] = wvv[k] / wsum;
            atomicAdd(&counts[selv[k]], 1);
        }
    }
}

// ---------------- prefix scan + counts/entropy -----------------
__global__ void scan_stats_kernel(const int* __restrict__ counts,
                                  int* __restrict__ offsets, int* __restrict__ cursor,
                                  float* __restrict__ out_tail)
{
    if (threadIdx.x == 0 && blockIdx.x == 0) {
        int off = 0; float tot = 0.f;
        for (int e = 0; e < E_NUM; ++e) {
            offsets[e] = off; cursor[e] = off; off += counts[e];
            tot += (float)counts[e];
        }
        offsets[E_NUM] = off;
        const float total = fmaxf(tot, 1.f);
        float ent = 0.f;
        for (int e = 0; e < E_NUM; ++e) {
            const float c = (float)counts[e];
            const float frac = c / total;
            ent -= frac * logf(frac + 1e-6f);
            out_tail[e] = c;
        }
        out_tail[E_NUM] = ent;
    }
}

// ---------------- expert-grouped permutation (+ inverse) -----------------
__global__ void scatter_kernel(const int* __restrict__ sel_idx,
                               int* __restrict__ cursor, int* __restrict__ perm,
                               int* __restrict__ inv)
{
    const int i = blockIdx.x * 256 + threadIdx.x;
    if (i >= T_TOK * K_TOP) return;
    const int e = sel_idx[i];
    const int pos = atomicAdd(&cursor[e], 1);
    perm[pos] = i;
    inv[i] = pos;
}

// ---------------- x fp32 -> bf16 -----------------
__global__ __launch_bounds__(256) void convert_x_kernel(
    const float* __restrict__ x, __bf16* __restrict__ xb)
{
    const int i = blockIdx.x * 256 + threadIdx.x;
    const float4 a = reinterpret_cast<const float4*>(x)[i * 2];
    const float4 b = reinterpret_cast<const float4*>(x)[i * 2 + 1];
    bf16x8 o;
    o[0] = (__bf16)a.x; o[1] = (__bf16)a.y; o[2] = (__bf16)a.z; o[3] = (__bf16)a.w;
    o[4] = (__bf16)b.x; o[5] = (__bf16)b.y; o[6] = (__bf16)b.z; o[7] = (__bf16)b.w;
    reinterpret_cast<bf16x8*>(xb)[i] = o;
}

// ---------------- weight transpose fp32 [e][R][C] -> bf16 [e][C][R] ----------
__global__ __launch_bounds__(256) void transpose_w_kernel(
    const float* __restrict__ in, __bf16* __restrict__ out, int R, int C)
{
    const int e = blockIdx.z;
    const int r0 = blockIdx.y * 32, c0 = blockIdx.x * 32;
    const int tid = threadIdx.x;
    const int r = tid >> 3, c4 = (tid & 7) * 4;
    __shared__ float lds[32][33];
    const float4 v = *reinterpret_cast<const float4*>(
        in + (size_t)e * R * C + (size_t)(r0 + r) * C + c0 + c4);
    lds[c4 + 0][r] = v.x; lds[c4 + 1][r] = v.y;
    lds[c4 + 2][r] = v.z; lds[c4 + 3][r] = v.w;
    __syncthreads();
    bf16x4 o;
    o[0] = (__bf16)lds[r][c4 + 0]; o[1] = (__bf16)lds[r][c4 + 1];
    o[2] = (__bf16)lds[r][c4 + 2]; o[3] = (__bf16)lds[r][c4 + 3];
    *reinterpret_cast<bf16x4*>(out + (size_t)e * R * C + (size_t)(c0 + r) * R + r0 + c4) = o;
}

// ---------------- gate/up MFMA GEMM: 128 rows x (32 g + 32 u cols) -----------
__global__ __launch_bounds__(256) void gate_mfma_kernel(
    const __bf16* __restrict__ xb, const __bf16* __restrict__ wguT,
    const int* __restrict__ offsets, const int* __restrict__ perm,
    const float* __restrict__ sel_w, __bf16* __restrict__ h)
{
    const int e = blockIdx.z;
    const int base = offsets[e];
    const int nrows = offsets[e + 1] - base;
    const int m0 = blockIdx.y * 128;
    if (m0 >= nrows) return;
    const int c0 = blockIdx.x * 32;           // g-col tile (0..511, 16 tiles)

    __shared__ __align__(16) __bf16 As[128 * 32];
    __shared__ __align__(16) __bf16 Bg[32 * 32];
    __shared__ __align__(16) __bf16 Bu[32 * 32];
    __shared__ int   tokrow[128];
    __shared__ float wrow[128];

    const int tid = threadIdx.x;
    const int wv = tid >> 6, lane = tid & 63;

    if (tid < 128) {
        const int gr = m0 + tid;
        const int grc = min(gr, nrows - 1);
        const int pv = perm[base + grc];
        tokrow[tid] = pv >> 2;
        wrow[tid] = (gr < nrows) ? sel_w[pv] : 0.f;
    }
    __syncthreads();

    const int ca0 = tid, ca1 = 256 + tid;
    const int ra0 = ca0 >> 2, ka0 = (ca0 & 3) ^ (ra0 & 3);
    const int ra1 = ca1 >> 2, ka1 = (ca1 & 3) ^ (ra1 & 3);
    const __bf16* a_src0 = xb + (size_t)tokrow[ra0] * D_DIM + ka0 * 8;
    const __bf16* a_src1 = xb + (size_t)tokrow[ra1] * D_DIM + ka1 * 8;
    const int cbl = tid & 127;
    const int rb = cbl >> 2, kb = (cbl & 3) ^ (rb & 3);
    const size_t wbase = (size_t)e * D_DIM * TWOI;
    const __bf16* b_src = wguT + wbase +
        (size_t)(c0 + (tid < 128 ? 0 : 512) + rb) * D_DIM + kb * 8;
    __bf16* a_dst0 = As + wv * 512;
    __bf16* a_dst1 = As + 2048 + wv * 512;
    __bf16* b_dst = (wv < 2 ? Bg + wv * 512 : Bu + (wv - 2) * 512);

    const int wr = wv >> 1, wc = wv & 1;
    int a_off[4];
#pragma unroll
    for (int m = 0; m < 4; ++m) {
        const int row = wr * 64 + m * 16 + (lane & 15);
        a_off[m] = row * 32 + (((lane >> 4) ^ (row & 3)) << 3);
    }
    const int col = wc * 16 + (lane & 15);
    const int b_off = col * 32 + (((lane >> 4) ^ (col & 3)) << 3);

    f32x4 accg[4] = {}; f32x4 accu[4] = {};
    for (int d0 = 0; d0 < D_DIM; d0 += 32) {
        gload_lds16(a_src0 + d0, a_dst0);
        gload_lds16(a_src1 + d0, a_dst1);
        gload_lds16(b_src + d0, b_dst);
        __syncthreads();
        bf16x8 af[4];
#pragma unroll
        for (int m = 0; m < 4; ++m) af[m] = *reinterpret_cast<const bf16x8*>(&As[a_off[m]]);
        const bf16x8 bgf = *reinterpret_cast<const bf16x8*>(&Bg[b_off]);
        const bf16x8 buf = *reinterpret_cast<const bf16x8*>(&Bu[b_off]);
#pragma unroll
        for (int m = 0; m < 4; ++m) {
            accg[m] = __builtin_amdgcn_mfma_f32_16x16x32_bf16(af[m], bgf, accg[m], 0, 0, 0);
            accu[m] = __builtin_amdgcn_mfma_f32_16x16x32_bf16(af[m], buf, accu[m], 0, 0, 0);
        }
        __syncthreads();
    }

    const int ocol = c0 + wc * 16 + (lane & 15);
#pragma unroll
    for (int m = 0; m < 4; ++m)
#pragma unroll
        for (int j = 0; j < 4; ++j) {
            const int lr = wr * 64 + m * 16 + (lane >> 4) * 4 + j;
            const int gr = m0 + lr;
            if (gr < nrows) {
                const float g = accg[m][j];
                const float u = accu[m][j];
                const float s = g / (1.f + expf(-g));
                h[(size_t)(base + gr) * I_DIM + ocol] = (__bf16)(s * u * wrow[lr]);
            }
        }
}

// ---------------- down MFMA GEMM: 128 rows x 64 cols, partial rows out -------
__global__ __launch_bounds__(256) void down_mfma_p_kernel(
    const __bf16* __restrict__ h, const __bf16* __restrict__ wdnT,
    const int* __restrict__ offsets, float* __restrict__ yp)
{
    const int e = blockIdx.z;
    const int base = offsets[e];
    const int nrows = offsets[e + 1] - base;
    const int m0 = blockIdx.y * 128;
    if (m0 >= nrows) return;
    const int c0 = blockIdx.x * 64;          // 16 col tiles

    __shared__ __align__(16) __bf16 As[128 * 32];
    __shared__ __align__(16) __bf16 Bs[64 * 32];

    const int tid = threadIdx.x;
    const int wv = tid >> 6, lane = tid & 63;

    const int ca0 = tid, ca1 = 256 + tid;
    const int ra0 = ca0 >> 2, ka0 = (ca0 & 3) ^ (ra0 & 3);
    const int ra1 = ca1 >> 2, ka1 = (ca1 & 3) ^ (ra1 & 3);
    const __bf16* a_src0 = h + (size_t)(base + min(m0 + ra0, nrows - 1)) * I_DIM + ka0 * 8;
    const __bf16* a_src1 = h + (size_t)(base + min(m0 + ra1, nrows - 1)) * I_DIM + ka1 * 8;
    const int rb = tid >> 2, kb = (tid & 3) ^ (rb & 3);
    const size_t wbase = (size_t)e * I_DIM * D_DIM;
    const __bf16* b_src = wdnT + wbase + (size_t)(c0 + rb) * I_DIM + kb * 8;
    __bf16* a_dst0 = As + wv * 512;
    __bf16* a_dst1 = As + 2048 + wv * 512;
    __bf16* b_dst = Bs + wv * 512;

    const int wr = wv >> 1, wc = wv & 1;
    int a_off[4], b_off[2];
#pragma unroll
    for (int m = 0; m < 4; ++m) {
        const int row = wr * 64 + m * 16 + (lane & 15);
        a_off[m] = row * 32 + (((lane >> 4) ^ (row & 3)) << 3);
    }
#pragma unroll
    for (int n = 0; n < 2; ++n) {
        const int col = wc * 32 + n * 16 + (lane & 15);
        b_off[n] = col * 32 + (((lane >> 4) ^ (col & 3)) << 3);
    }

    f32x4 acc[4][2] = {};
    for (int d0 = 0; d0 < I_DIM; d0 += 32) {
        gload_lds16(a_src0 + d0, a_dst0);
        gload_lds16(a_src1 + d0, a_dst1);
        gload_lds16(b_src + d0, b_dst);
        __syncthreads();
        bf16x8 af[4], bf[2];
#pragma unroll
        for (int m = 0; m < 4; ++m) af[m] = *reinterpret_cast<const bf16x8*>(&As[a_off[m]]);
#pragma unroll
        for (int n = 0; n < 2; ++n) bf[n] = *reinterpret_cast<const bf16x8*>(&Bs[b_off[n]]);
#pragma unroll
        for (int m = 0; m < 4; ++m)
#pragma unroll
            for (int n = 0; n < 2; ++n)
                acc[m][n] = __builtin_amdgcn_mfma_f32_16x16x32_bf16(af[m], bf[n], acc[m][n], 0, 0, 0);
        __syncthreads();
    }

#pragma unroll
    for (int m = 0; m < 4; ++m)
#pragma unroll
        for (int j = 0; j < 4; ++j) {
            const int lr = wr * 64 + m * 16 + (lane >> 4) * 4 + j;
            const int gr = m0 + lr;
            if (gr < nrows) {
#pragma unroll
                for (int n = 0; n < 2; ++n) {
                    const int col = c0 + wc * 32 + n * 16 + (lane & 15);
                    yp[(size_t)(base + gr) * D_DIM + col] = acc[m][n][j];
                }
            }
        }
}

// ---------------- combine: y[t] = sum_k yp[inv[t*4+k]] -----------------------
__global__ __launch_bounds__(256) void combine_kernel(
    const float* __restrict__ yp, const int* __restrict__ inv, float* __restrict__ y)
{
    const int t = blockIdx.x, tid = threadIdx.x;
    const int r0 = inv[t * 4 + 0], r1 = inv[t * 4 + 1];
    const int r2 = inv[t * 4 + 2], r3 = inv[t * 4 + 3];
    const float4 a = reinterpret_cast<const float4*>(yp + (size_t)r0 * D_DIM)[tid];
    const float4 b = reinterpret_cast<const float4*>(yp + (size_t)r1 * D_DIM)[tid];
    const float4 c = reinterpret_cast<const float4*>(yp + (size_t)r2 * D_DIM)[tid];
    const float4 d = reinterpret_cast<const float4*>(yp + (size_t)r3 * D_DIM)[tid];
    float4 s;
    s.x = (a.x + b.x) + (c.x + d.x);
    s.y = (a.y + b.y) + (c.y + d.y);
    s.z = (a.z + b.z) + (c.z + d.z);
    s.w = (a.w + b.w) + (c.w + d.w);
    reinterpret_cast<float4*>(y + (size_t)t * D_DIM)[tid] = s;
}

// ---------------- down MFMA GEMM (mid tier): 128x128, atomic scatter ---------
__global__ __launch_bounds__(256) void down_mfma_kernel(
    const __bf16* __restrict__ h, const __bf16* __restrict__ wdnT,
    const int* __restrict__ offsets, const int* __restrict__ perm,
    float* __restrict__ y)
{
    const int e = blockIdx.z;
    const int base = offsets[e];
    const int nrows = offsets[e + 1] - base;
    const int m0 = blockIdx.y * 128;
    if (m0 >= nrows) return;
    const int c0 = blockIdx.x * 128;

    __shared__ __align__(16) __bf16 As[128 * 32];
    __shared__ __align__(16) __bf16 Bs[128 * 32];
    __shared__ int tokrow[128];

    const int tid = threadIdx.x;
    const int wv = tid >> 6, lane = tid & 63;

    if (tid < 128) {
        const int gr = m0 + tid;
        const int grc = min(gr, nrows - 1);
        tokrow[tid] = perm[base + grc] >> 2;
    }
    __syncthreads();

    const int ca0 = wv * 64 + lane, ca1 = 256 + wv * 64 + lane;
    const int ra0 = ca0 >> 2, ka0 = (ca0 & 3) ^ (ra0 & 3);
    const int ra1 = ca1 >> 2, ka1 = (ca1 & 3) ^ (ra1 & 3);
    const __bf16* a_src0 = h + (size_t)(base + min(m0 + ra0, nrows - 1)) * I_DIM + ka0 * 8;
    const __bf16* a_src1 = h + (size_t)(base + min(m0 + ra1, nrows - 1)) * I_DIM + ka1 * 8;
    const size_t wbase = (size_t)e * I_DIM * D_DIM;
    const __bf16* b_src0 = wdnT + wbase + (size_t)(c0 + ra0) * I_DIM + ka0 * 8;
    const __bf16* b_src1 = wdnT + wbase + (size_t)(c0 + ra1) * I_DIM + ka1 * 8;
    __bf16* a_dst0 = As + wv * 512;
    __bf16* a_dst1 = As + 2048 + wv * 512;
    __bf16* b_dst0 = Bs + wv * 512;
    __bf16* b_dst1 = Bs + 2048 + wv * 512;

    const int wr = wv >> 1, wc = wv & 1;
    int a_off[4], b_off[4];
#pragma unroll
    for (int m = 0; m < 4; ++m) {
        const int row = wr * 64 + m * 16 + (lane & 15);
        a_off[m] = row * 32 + (((lane >> 4) ^ (row & 3)) << 3);
        const int col = wc * 64 + m * 16 + (lane & 15);
        b_off[m] = col * 32 + (((lane >> 4) ^ (col & 3)) << 3);
    }

    f32x4 acc[4][4] = {};
    for (int d0 = 0; d0 < I_DIM; d0 += 32) {
        gload_lds16(a_src0 + d0, a_dst0);
        gload_lds16(a_src1 + d0, a_dst1);
        gload_lds16(b_src0 + d0, b_dst0);
        gload_lds16(b_src1 + d0, b_dst1);
        __syncthreads();
        bf16x8 af[4], bf[4];
#pragma unroll
        for (int m = 0; m < 4; ++m) {
            af[m] = *reinterpret_cast<const bf16x8*>(&As[a_off[m]]);
            bf[m] = *reinterpret_cast<const bf16x8*>(&Bs[b_off[m]]);
        }
#pragma unroll
        for (int m = 0; m < 4; ++m)
#pragma unroll
            for (int n = 0; n < 4; ++n)
                acc[m][n] = __builtin_amdgcn_mfma_f32_16x16x32_bf16(af[m], bf[n], acc[m][n], 0, 0, 0);
        __syncthreads();
    }

#pragma unroll
    for (int m = 0; m < 4; ++m)
#pragma unroll
        for (int j = 0; j < 4; ++j) {
            const int lr = wr * 64 + m * 16 + (lane >> 4) * 4 + j;
            const int gr = m0 + lr;
            if (gr < nrows) {
                const int tok = tokrow[lr];
#pragma unroll
                for (int n = 0; n < 4; ++n) {
                    const int col = c0 + wc * 64 + n * 16 + (lane & 15);
                    atomicAdd(&y[(size_t)tok * D_DIM + col], acc[m][n][j]);
                }
            }
        }
}

// ================= fallback fp32 path (round-0, proven) ======================
__global__ __launch_bounds__(256) void gate_gemm_kernel(
    const float* __restrict__ x, const float* __restrict__ wgu,
    const int* __restrict__ offsets, const int* __restrict__ perm,
    const float* __restrict__ sel_w, float* __restrict__ h)
{
    const int e = blockIdx.z;
    const int base = offsets[e];
    const int nrows = offsets[e + 1] - base;
    const int m0 = blockIdx.y * 64;
    if (m0 >= nrows) return;
    const int c0 = blockIdx.x * 64;
    const int tid = threadIdx.x;
    __shared__ float As[16][64];
    __shared__ float Bg[16][64];
    __shared__ float Bu[16][64];
    const int lrow = tid >> 2;
    const int c4 = (tid & 3) * 4;
    const int grow = m0 + lrow;
    const bool arow_ok = (grow < nrows);
    const float* xrow = nullptr;
    if (arow_ok) {
        const int pv = perm[base + grow];
        xrow = x + (size_t)(pv >> 2) * D_DIM;
    }
    const int bcol = tid & 63;
    const int brow0 = tid >> 6;
    const float* wbase = wgu + (size_t)e * D_DIM * TWOI;
    const int tx = tid & 15, ty = tid >> 4;
    float accg[4][4] = {}, accu[4][4] = {};
    for (int d0 = 0; d0 < D_DIM; d0 += 16) {
        float4 av = make_float4(0.f, 0.f, 0.f, 0.f);
        if (arow_ok) av = *reinterpret_cast<const float4*>(xrow + d0 + c4);
        As[c4 + 0][lrow] = av.x; As[c4 + 1][lrow] = av.y;
        As[c4 + 2][lrow] = av.z; As[c4 + 3][lrow] = av.w;
#pragma unroll
        for (int r = 0; r < 4; ++r) {
            const int dd = d0 + brow0 + r * 4;
            const float* wr = wbase + (size_t)dd * TWOI;
            Bg[brow0 + r * 4][bcol] = wr[c0 + bcol];
            Bu[brow0 + r * 4][bcol] = wr[c0 + 512 + bcol];
        }
        __syncthreads();
#pragma unroll
        for (int kk = 0; kk < 16; ++kk) {
            const float4 a  = *reinterpret_cast<const float4*>(&As[kk][ty * 4]);
            const float4 bg = *reinterpret_cast<const float4*>(&Bg[kk][tx * 4]);
            const float4 bu = *reinterpret_cast<const float4*>(&Bu[kk][tx * 4]);
            const float aa[4] = { a.x, a.y, a.z, a.w };
            const float gg[4] = { bg.x, bg.y, bg.z, bg.w };
            const float uu[4] = { bu.x, bu.y, bu.z, bu.w };
#pragma unroll
            for (int i2 = 0; i2 < 4; ++i2)
#pragma unroll
                for (int j = 0; j < 4; ++j) {
                    accg[i2][j] += aa[i2] * gg[j];
                    accu[i2][j] += aa[i2] * uu[j];
                }
        }
        __syncthreads();
    }
#pragma unroll
    for (int i2 = 0; i2 < 4; ++i2) {
        const int r = ty * 4 + i2;
        const int gr = m0 + r;
        if (gr < nrows) {
            const int pv = perm[base + gr];
            const float wgt = sel_w[pv];
            float* hrow = h + (size_t)(base + gr) * I_DIM + c0;
#pragma unroll
            for (int j = 0; j < 4; ++j) {
                const float g = accg[i2][j];
                const float u = accu[i2][j];
                const float s = g / (1.f + expf(-g));
                hrow[tx * 4 + j] = s * u * wgt;
            }
        }
    }
}

__global__ __launch_bounds__(256) void down_gemm_kernel(
    const float* __restrict__ h, const float* __restrict__ wdn,
    const int* __restrict__ offsets, const int* __restrict__ perm,
    float* __restrict__ y)
{
    const int e = blockIdx.z;
    const int base = offsets[e];
    const int nrows = offsets[e + 1] - base;
    const int m0 = blockIdx.y * 64;
    if (m0 >= nrows) return;
    const int c0 = blockIdx.x * 64;
    const int tid = threadIdx.x;
    __shared__ float As[16][64];
    __shared__ float Bs[16][64];
    const int lrow = tid >> 2;
    const int c4 = (tid & 3) * 4;
    const int grow = m0 + lrow;
    const bool arow_ok = (grow < nrows);
    const float* hrow = arow_ok ? (h + (size_t)(base + grow) * I_DIM) : nullptr;
    const int bcol = tid & 63;
    const int brow0 = tid >> 6;
    const float* wbase = wdn + (size_t)e * I_DIM * D_DIM;
    const int tx = tid & 15, ty = tid >> 4;
    float acc[4][4] = {};
    for (int d0 = 0; d0 < I_DIM; d0 += 16) {
        float4 av = make_float4(0.f, 0.f, 0.f, 0.f);
        if (arow_ok) av = *reinterpret_cast<const float4*>(hrow + d0 + c4);
        As[c4 + 0][lrow] = av.x; As[c4 + 1][lrow] = av.y;
        As[c4 + 2][lrow] = av.z; As[c4 + 3][lrow] = av.w;
#pragma unroll
        for (int r = 0; r < 4; ++r) {
            const int dd = d0 + brow0 + r * 4;
            Bs[brow0 + r * 4][bcol] = wbase[(size_t)dd * D_DIM + c0 + bcol];
        }
        __syncthreads();
#pragma unroll
        for (int kk = 0; kk < 16; ++kk) {
            const float4 a = *reinterpret_cast<const float4*>(&As[kk][ty * 4]);
            const float4 b = *reinterpret_cast<const float4*>(&Bs[kk][tx * 4]);
            const float aa[4] = { a.x, a.y, a.z, a.w };
            const float bb[4] = { b.x, b.y, b.z, b.w };
#pragma unroll
            for (int i2 = 0; i2 < 4; ++i2)
#pragma unroll
                for (int j = 0; j < 4; ++j)
                    acc[i2][j] += aa[i2] * bb[j];
        }
        __syncthreads();
    }
#pragma unroll
    for (int i2 = 0; i2 < 4; ++i2) {
        const int r = ty * 4 + i2;
        const int gr = m0 + r;
        if (gr < nrows) {
            const int pv = perm[base + gr];
            const int t = pv >> 2;
            float* yrow = y + (size_t)t * D_DIM + c0;
#pragma unroll
            for (int j = 0; j < 4; ++j)
                atomicAdd(&yrow[tx * 4 + j], acc[i2][j]);
        }
    }
}

// ---------------- launch -----------------------------------------------------
extern "C" void kernel_launch(void* const* d_in, const int* in_sizes, int n_in,
                              void* d_out, int out_size, void* d_ws, size_t ws_size,
                              hipStream_t stream)
{
    const float* x      = (const float*)d_in[0];
    const float* router = (const float*)d_in[1];
    const float* rbias  = (const float*)d_in[2];
    const float* wgu    = (const float*)d_in[3];
    const float* wdn    = (const float*)d_in[4];
    float* out = (float*)d_out;

    char* ws = (char*)d_ws;
    int*   sel_idx = (int*)(ws);                    // 32 KB
    float* sel_w   = (float*)(ws + 32768);          // 32 KB
    int*   perm    = (int*)(ws + 65536);            // 32 KB
    int*   inv     = (int*)(ws + 98304);            // 32 KB
    int*   counts  = (int*)(ws + 131072);
    int*   offsets = (int*)(ws + 131328);
    int*   cursor  = (int*)(ws + 131584);
    __bf16* xb     = (__bf16*)(ws + 262144);        // 4 MB
    __bf16* hb     = (__bf16*)(ws + 4456448);       // 8 MB
    __bf16* wguT   = (__bf16*)(ws + 12845056);      // 32 MB
    __bf16* wdnT   = (__bf16*)(ws + 46399488);      // 16 MB -> 63176704
    float* yp      = (float*)(ws + 63242240);       // 32 MB -> 96796672
    float* hf      = (float*)(ws + 262144);         // fallback fp32 h (16.8 MB)

    const bool fast = (ws_size >= 96796672ULL);
    const bool mid  = (ws_size >= 63242240ULL);

    hipMemsetAsync(counts, 0, 64, stream);
    if (!fast)
        hipMemsetAsync(out, 0, (size_t)T_TOK * D_DIM * sizeof(float), stream);

    router_wave2_kernel<<<T_TOK / 4, 256, 0, stream>>>(x, router, rbias, sel_idx, sel_w, counts);
    scan_stats_kernel<<<1, 64, 0, stream>>>(counts, offsets, cursor,
                                            out + (size_t)T_TOK * D_DIM);
    scatter_kernel<<<(T_TOK * K_TOP + 255) / 256, 256, 0, stream>>>(sel_idx, cursor, perm, inv);

    if (mid) {
        convert_x_kernel<<<T_TOK * D_DIM / 8 / 256, 256, 0, stream>>>(x, xb);
        transpose_w_kernel<<<dim3(TWOI / 32, D_DIM / 32, E_NUM), 256, 0, stream>>>(wgu, wguT, D_DIM, TWOI);
        transpose_w_kernel<<<dim3(D_DIM / 32, I_DIM / 32, E_NUM), 256, 0, stream>>>(wdn, wdnT, I_DIM, D_DIM);
        gate_mfma_kernel<<<dim3(16, 16, E_NUM), 256, 0, stream>>>(xb, wguT, offsets, perm, sel_w, hb);
        if (fast) {
            down_mfma_p_kernel<<<dim3(16, 16, E_NUM), 256, 0, stream>>>(hb, wdnT, offsets, yp);
            combine_kernel<<<T_TOK, 256, 0, stream>>>(yp, inv, out);
        } else {
            down_mfma_kernel<<<dim3(8, 16, E_NUM), 256, 0, stream>>>(hb, wdnT, offsets, perm, out);
        }
    } else {
        gate_gemm_kernel<<<dim3(8, 32, E_NUM), 256, 0, stream>>>(x, wgu, offsets, perm, sel_w, hf);
        down_gemm_kernel<<<dim3(16, 32, E_NUM), 256, 0, stream>>>(hf, wdn, offsets, perm, out);
    }
}

// Round 8
// 281.669 us; speedup vs baseline: 1.2770x; 1.2770x over previous
//
#include <hip/hip_runtime.h>
#include <hip/hip_bf16.h>
#include <cstdint>

#define T_TOK 2048
#define D_DIM 1024
#define E_NUM 16
#define K_TOP 4
#define I_DIM 512
#define TWOI  1024
#define RT_TOK 16
#define XST   258

typedef __bf16 bf16x8 __attribute__((ext_vector_type(8)));
typedef __bf16 bf16x4 __attribute__((ext_vector_type(4)));
typedef float  f32x4  __attribute__((ext_vector_type(4)));

__device__ __forceinline__ void gload_lds16(const void* g, void* l) {
    __builtin_amdgcn_global_load_lds(
        (const __attribute__((address_space(1))) void*)(uintptr_t)(g),
        (__attribute__((address_space(3))) void*)(uintptr_t)(l),
        16, 0, 0);
}

// ---------------- router: LDS-staged, fully coalesced, fp32 exact ------------
// 16 tokens/block. 4 chunks of 256 d: router chunk [256][16] rotated, x chunk
// [16][258]. Thread (t,q) accumulates acc[16] over its 16 d's per chunk.
__global__ __launch_bounds__(256) void router_lds_kernel(
    const float* __restrict__ x, const float* __restrict__ router,
    const float* __restrict__ rbias,
    int* __restrict__ sel_idx, float* __restrict__ sel_w, int* __restrict__ counts)
{
    __shared__ float rl[256 * 16];          // 16 KB, float4-group rotated
    __shared__ float xs[RT_TOK * XST];      // 16.5 KB
    __shared__ float red2[4 * RT_TOK * 16]; // 4 KB
    __shared__ float lgs[RT_TOK * 16];      // 1 KB

    const int tid = threadIdx.x;
    const int t0 = blockIdx.x * RT_TOK;
    const int t = tid & 15, q = tid >> 4;   // token lane, d-subrange 0..15
    const int lane = tid & 63, wv = tid >> 6;

    float acc[E_NUM];
#pragma unroll
    for (int e = 0; e < E_NUM; ++e) acc[e] = 0.f;

    for (int c = 0; c < 4; ++c) {
        // stage router chunk (coalesced 64B rows; rotate groups by (row>>4)&3)
        {
            const float* rg = router + (size_t)(c * 256 + tid) * E_NUM;
            const int rot = (tid >> 4) & 3;
#pragma unroll
            for (int g = 0; g < 4; ++g) {
                const f32x4 v = *reinterpret_cast<const f32x4*>(rg + g * 4);
                *reinterpret_cast<f32x4*>(&rl[tid * 16 + ((g + rot) & 3) * 4]) = v;
            }
        }
        // stage x chunk (coalesced float4 reads; float2 LDS writes, stride 258)
        {
            const int r = tid >> 4, cb = (tid & 15) * 16;
            const float* xg = x + (size_t)(t0 + r) * D_DIM + c * 256 + cb;
            float v[16];
#pragma unroll
            for (int g = 0; g < 4; ++g) {
                const f32x4 vv = *reinterpret_cast<const f32x4*>(xg + g * 4);
                v[g*4+0] = vv[0]; v[g*4+1] = vv[1]; v[g*4+2] = vv[2]; v[g*4+3] = vv[3];
            }
            float* xd = &xs[r * XST + cb];
#pragma unroll
            for (int i = 0; i < 8; ++i) {
                float2 w; w.x = v[i*2]; w.y = v[i*2+1];
                *reinterpret_cast<float2*>(xd + i * 2) = w;
            }
        }
        __syncthreads();
        // compute: 16 d's for this (t,q); router reads are 16-lane broadcasts
#pragma unroll
        for (int j = 0; j < 16; ++j) {
            const int dl = q * 16 + j;
            const float xv = xs[t * XST + dl];
#pragma unroll
            for (int g = 0; g < 4; ++g) {
                const f32x4 rv = *reinterpret_cast<const f32x4*>(
                    &rl[dl * 16 + ((g + q) & 3) * 4]);
#pragma unroll
                for (int i = 0; i < 4; ++i)
                    acc[g * 4 + i] += xv * rv[i];
            }
        }
        __syncthreads();
    }

    // fold the 4 in-wave q's (lanes 16 apart), then 4 waves via LDS
#pragma unroll
    for (int e = 0; e < E_NUM; ++e) {
        acc[e] += __shfl_xor(acc[e], 16);
        acc[e] += __shfl_xor(acc[e], 32);
    }
    if (lane < 16) {
#pragma unroll
        for (int g = 0; g < 4; ++g) {
            f32x4 v; v[0] = acc[g*4]; v[1] = acc[g*4+1]; v[2] = acc[g*4+2]; v[3] = acc[g*4+3];
            *reinterpret_cast<f32x4*>(&red2[(wv * RT_TOK + lane) * 16 + g * 4]) = v;
        }
    }
    __syncthreads();
    {
        const int tt = tid >> 4, ee = tid & 15;
        const float s = red2[(0 * RT_TOK + tt) * 16 + ee]
                      + red2[(1 * RT_TOK + tt) * 16 + ee]
                      + red2[(2 * RT_TOK + tt) * 16 + ee]
                      + red2[(3 * RT_TOK + tt) * 16 + ee];
        lgs[tt * 16 + ee] = s;
    }
    __syncthreads();
    if (tid < RT_TOK) {
        const int tok = t0 + tid;
        float lg[E_NUM], bi[E_NUM];
#pragma unroll
        for (int j = 0; j < E_NUM; ++j) { lg[j] = lgs[tid * 16 + j]; bi[j] = lg[j] + rbias[j]; }
        bool used[E_NUM];
#pragma unroll
        for (int j = 0; j < E_NUM; ++j) used[j] = false;
        int selv[K_TOP]; float wvv[K_TOP]; float wsum = 0.f;
#pragma unroll
        for (int k = 0; k < K_TOP; ++k) {
            float best = -1e30f; int bidx = 0;
#pragma unroll
            for (int j = 0; j < E_NUM; ++j)
                if (!used[j] && bi[j] > best) { best = bi[j]; bidx = j; }
            used[bidx] = true; selv[k] = bidx;
            const float s = 1.f / (1.f + expf(-lg[bidx]));
            wvv[k] = s; wsum += s;
        }
#pragma unroll
        for (int k = 0; k < K_TOP; ++k) {
            sel_idx[tok * K_TOP + k] = selv[k];
            sel_w[tok * K_TOP + k] = wvv[k] / wsum;
            atomicAdd(&counts[selv[k]], 1);
        }
    }
}

// ---------------- prefix scan + counts/entropy -----------------
__global__ void scan_stats_kernel(const int* __restrict__ counts,
                                  int* __restrict__ offsets, int* __restrict__ cursor,
                                  float* __restrict__ out_tail)
{
    if (threadIdx.x == 0 && blockIdx.x == 0) {
        int off = 0; float tot = 0.f;
        for (int e = 0; e < E_NUM; ++e) {
            offsets[e] = off; cursor[e] = off; off += counts[e];
            tot += (float)counts[e];
        }
        offsets[E_NUM] = off;
        const float total = fmaxf(tot, 1.f);
        float ent = 0.f;
        for (int e = 0; e < E_NUM; ++e) {
            const float c = (float)counts[e];
            const float frac = c / total;
            ent -= frac * logf(frac + 1e-6f);
            out_tail[e] = c;
        }
        out_tail[E_NUM] = ent;
    }
}

// ---------------- expert-grouped permutation (+ inverse) -----------------
__global__ void scatter_kernel(const int* __restrict__ sel_idx,
                               int* __restrict__ cursor, int* __restrict__ perm,
                               int* __restrict__ inv)
{
    const int i = blockIdx.x * 256 + threadIdx.x;
    if (i >= T_TOK * K_TOP) return;
    const int e = sel_idx[i];
    const int pos = atomicAdd(&cursor[e], 1);
    perm[pos] = i;
    inv[i] = pos;
}

// ---------------- x fp32 -> bf16 -----------------
__global__ __launch_bounds__(256) void convert_x_kernel(
    const float* __restrict__ x, __bf16* __restrict__ xb)
{
    const int i = blockIdx.x * 256 + threadIdx.x;
    const float4 a = reinterpret_cast<const float4*>(x)[i * 2];
    const float4 b = reinterpret_cast<const float4*>(x)[i * 2 + 1];
    bf16x8 o;
    o[0] = (__bf16)a.x; o[1] = (__bf16)a.y; o[2] = (__bf16)a.z; o[3] = (__bf16)a.w;
    o[4] = (__bf16)b.x; o[5] = (__bf16)b.y; o[6] = (__bf16)b.z; o[7] = (__bf16)b.w;
    reinterpret_cast<bf16x8*>(xb)[i] = o;
}

// ---------------- weight transpose fp32 [e][R][C] -> bf16 [e][C][R] ----------
__global__ __launch_bounds__(256) void transpose_w_kernel(
    const float* __restrict__ in, __bf16* __restrict__ out, int R, int C)
{
    const int e = blockIdx.z;
    const int r0 = blockIdx.y * 32, c0 = blockIdx.x * 32;
    const int tid = threadIdx.x;
    const int r = tid >> 3, c4 = (tid & 7) * 4;
    __shared__ float lds[32][33];
    const float4 v = *reinterpret_cast<const float4*>(
        in + (size_t)e * R * C + (size_t)(r0 + r) * C + c0 + c4);
    lds[c4 + 0][r] = v.x; lds[c4 + 1][r] = v.y;
    lds[c4 + 2][r] = v.z; lds[c4 + 3][r] = v.w;
    __syncthreads();
    bf16x4 o;
    o[0] = (__bf16)lds[r][c4 + 0]; o[1] = (__bf16)lds[r][c4 + 1];
    o[2] = (__bf16)lds[r][c4 + 2]; o[3] = (__bf16)lds[r][c4 + 3];
    *reinterpret_cast<bf16x4*>(out + (size_t)e * R * C + (size_t)(c0 + r) * R + r0 + c4) = o;
}

// ---------------- gate/up MFMA GEMM: 128 rows x (32 g + 32 u cols) -----------
__global__ __launch_bounds__(256) void gate_mfma_kernel(
    const __bf16* __restrict__ xb, const __bf16* __restrict__ wguT,
    const int* __restrict__ offsets, const int* __restrict__ perm,
    const float* __restrict__ sel_w, __bf16* __restrict__ h)
{
    const int e = blockIdx.z;
    const int base = offsets[e];
    const int nrows = offsets[e + 1] - base;
    const int m0 = blockIdx.y * 128;
    if (m0 >= nrows) return;
    const int c0 = blockIdx.x * 32;

    __shared__ __align__(16) __bf16 As[128 * 32];
    __shared__ __align__(16) __bf16 Bg[32 * 32];
    __shared__ __align__(16) __bf16 Bu[32 * 32];
    __shared__ int   tokrow[128];
    __shared__ float wrow[128];

    const int tid = threadIdx.x;
    const int wv = tid >> 6, lane = tid & 63;

    if (tid < 128) {
        const int gr = m0 + tid;
        const int grc = min(gr, nrows - 1);
        const int pv = perm[base + grc];
        tokrow[tid] = pv >> 2;
        wrow[tid] = (gr < nrows) ? sel_w[pv] : 0.f;
    }
    __syncthreads();

    const int ca0 = tid, ca1 = 256 + tid;
    const int ra0 = ca0 >> 2, ka0 = (ca0 & 3) ^ (ra0 & 3);
    const int ra1 = ca1 >> 2, ka1 = (ca1 & 3) ^ (ra1 & 3);
    const __bf16* a_src0 = xb + (size_t)tokrow[ra0] * D_DIM + ka0 * 8;
    const __bf16* a_src1 = xb + (size_t)tokrow[ra1] * D_DIM + ka1 * 8;
    const int cbl = tid & 127;
    const int rb = cbl >> 2, kb = (cbl & 3) ^ (rb & 3);
    const size_t wbase = (size_t)e * D_DIM * TWOI;
    const __bf16* b_src = wguT + wbase +
        (size_t)(c0 + (tid < 128 ? 0 : 512) + rb) * D_DIM + kb * 8;
    __bf16* a_dst0 = As + wv * 512;
    __bf16* a_dst1 = As + 2048 + wv * 512;
    __bf16* b_dst = (wv < 2 ? Bg + wv * 512 : Bu + (wv - 2) * 512);

    const int wr = wv >> 1, wc = wv & 1;
    int a_off[4];
#pragma unroll
    for (int m = 0; m < 4; ++m) {
        const int row = wr * 64 + m * 16 + (lane & 15);
        a_off[m] = row * 32 + (((lane >> 4) ^ (row & 3)) << 3);
    }
    const int col = wc * 16 + (lane & 15);
    const int b_off = col * 32 + (((lane >> 4) ^ (col & 3)) << 3);

    f32x4 accg[4] = {}; f32x4 accu[4] = {};
    for (int d0 = 0; d0 < D_DIM; d0 += 32) {
        gload_lds16(a_src0 + d0, a_dst0);
        gload_lds16(a_src1 + d0, a_dst1);
        gload_lds16(b_src + d0, b_dst);
        __syncthreads();
        bf16x8 af[4];
#pragma unroll
        for (int m = 0; m < 4; ++m) af[m] = *reinterpret_cast<const bf16x8*>(&As[a_off[m]]);
        const bf16x8 bgf = *reinterpret_cast<const bf16x8*>(&Bg[b_off]);
        const bf16x8 buf = *reinterpret_cast<const bf16x8*>(&Bu[b_off]);
#pragma unroll
        for (int m = 0; m < 4; ++m) {
            accg[m] = __builtin_amdgcn_mfma_f32_16x16x32_bf16(af[m], bgf, accg[m], 0, 0, 0);
            accu[m] = __builtin_amdgcn_mfma_f32_16x16x32_bf16(af[m], buf, accu[m], 0, 0, 0);
        }
        __syncthreads();
    }

    const int ocol = c0 + wc * 16 + (lane & 15);
#pragma unroll
    for (int m = 0; m < 4; ++m)
#pragma unroll
        for (int j = 0; j < 4; ++j) {
            const int lr = wr * 64 + m * 16 + (lane >> 4) * 4 + j;
            const int gr = m0 + lr;
            if (gr < nrows) {
                const float g = accg[m][j];
                const float u = accu[m][j];
                const float s = g / (1.f + expf(-g));
                h[(size_t)(base + gr) * I_DIM + ocol] = (__bf16)(s * u * wrow[lr]);
            }
        }
}

// ---------------- down MFMA GEMM: 128 rows x 64 cols, partial rows out -------
__global__ __launch_bounds__(256) void down_mfma_p_kernel(
    const __bf16* __restrict__ h, const __bf16* __restrict__ wdnT,
    const int* __restrict__ offsets, float* __restrict__ yp)
{
    const int e = blockIdx.z;
    const int base = offsets[e];
    const int nrows = offsets[e + 1] - base;
    const int m0 = blockIdx.y * 128;
    if (m0 >= nrows) return;
    const int c0 = blockIdx.x * 64;

    __shared__ __align__(16) __bf16 As[128 * 32];
    __shared__ __align__(16) __bf16 Bs[64 * 32];

    const int tid = threadIdx.x;
    const int wv = tid >> 6, lane = tid & 63;

    const int ca0 = tid, ca1 = 256 + tid;
    const int ra0 = ca0 >> 2, ka0 = (ca0 & 3) ^ (ra0 & 3);
    const int ra1 = ca1 >> 2, ka1 = (ca1 & 3) ^ (ra1 & 3);
    const __bf16* a_src0 = h + (size_t)(base + min(m0 + ra0, nrows - 1)) * I_DIM + ka0 * 8;
    const __bf16* a_src1 = h + (size_t)(base + min(m0 + ra1, nrows - 1)) * I_DIM + ka1 * 8;
    const int rb = tid >> 2, kb = (tid & 3) ^ (rb & 3);
    const size_t wbase = (size_t)e * I_DIM * D_DIM;
    const __bf16* b_src = wdnT + wbase + (size_t)(c0 + rb) * I_DIM + kb * 8;
    __bf16* a_dst0 = As + wv * 512;
    __bf16* a_dst1 = As + 2048 + wv * 512;
    __bf16* b_dst = Bs + wv * 512;

    const int wr = wv >> 1, wc = wv & 1;
    int a_off[4], b_off[2];
#pragma unroll
    for (int m = 0; m < 4; ++m) {
        const int row = wr * 64 + m * 16 + (lane & 15);
        a_off[m] = row * 32 + (((lane >> 4) ^ (row & 3)) << 3);
    }
#pragma unroll
    for (int n = 0; n < 2; ++n) {
        const int col = wc * 32 + n * 16 + (lane & 15);
        b_off[n] = col * 32 + (((lane >> 4) ^ (col & 3)) << 3);
    }

    f32x4 acc[4][2] = {};
    for (int d0 = 0; d0 < I_DIM; d0 += 32) {
        gload_lds16(a_src0 + d0, a_dst0);
        gload_lds16(a_src1 + d0, a_dst1);
        gload_lds16(b_src + d0, b_dst);
        __syncthreads();
        bf16x8 af[4], bf[2];
#pragma unroll
        for (int m = 0; m < 4; ++m) af[m] = *reinterpret_cast<const bf16x8*>(&As[a_off[m]]);
#pragma unroll
        for (int n = 0; n < 2; ++n) bf[n] = *reinterpret_cast<const bf16x8*>(&Bs[b_off[n]]);
#pragma unroll
        for (int m = 0; m < 4; ++m)
#pragma unroll
            for (int n = 0; n < 2; ++n)
                acc[m][n] = __builtin_amdgcn_mfma_f32_16x16x32_bf16(af[m], bf[n], acc[m][n], 0, 0, 0);
        __syncthreads();
    }

#pragma unroll
    for (int m = 0; m < 4; ++m)
#pragma unroll
        for (int j = 0; j < 4; ++j) {
            const int lr = wr * 64 + m * 16 + (lane >> 4) * 4 + j;
            const int gr = m0 + lr;
            if (gr < nrows) {
#pragma unroll
                for (int n = 0; n < 2; ++n) {
                    const int col = c0 + wc * 32 + n * 16 + (lane & 15);
                    yp[(size_t)(base + gr) * D_DIM + col] = acc[m][n][j];
                }
            }
        }
}

// ---------------- combine: y[t] = sum_k yp[inv[t*4+k]] -----------------------
__global__ __launch_bounds__(256) void combine_kernel(
    const float* __restrict__ yp, const int* __restrict__ inv, float* __restrict__ y)
{
    const int t = blockIdx.x, tid = threadIdx.x;
    const int r0 = inv[t * 4 + 0], r1 = inv[t * 4 + 1];
    const int r2 = inv[t * 4 + 2], r3 = inv[t * 4 + 3];
    const float4 a = reinterpret_cast<const float4*>(yp + (size_t)r0 * D_DIM)[tid];
    const float4 b = reinterpret_cast<const float4*>(yp + (size_t)r1 * D_DIM)[tid];
    const float4 c = reinterpret_cast<const float4*>(yp + (size_t)r2 * D_DIM)[tid];
    const float4 d = reinterpret_cast<const float4*>(yp + (size_t)r3 * D_DIM)[tid];
    float4 s;
    s.x = (a.x + b.x) + (c.x + d.x);
    s.y = (a.y + b.y) + (c.y + d.y);
    s.z = (a.z + b.z) + (c.z + d.z);
    s.w = (a.w + b.w) + (c.w + d.w);
    reinterpret_cast<float4*>(y + (size_t)t * D_DIM)[tid] = s;
}

// ---------------- down MFMA GEMM (mid tier): 128x128, atomic scatter ---------
__global__ __launch_bounds__(256) void down_mfma_kernel(
    const __bf16* __restrict__ h, const __bf16* __restrict__ wdnT,
    const int* __restrict__ offsets, const int* __restrict__ perm,
    float* __restrict__ y)
{
    const int e = blockIdx.z;
    const int base = offsets[e];
    const int nrows = offsets[e + 1] - base;
    const int m0 = blockIdx.y * 128;
    if (m0 >= nrows) return;
    const int c0 = blockIdx.x * 128;

    __shared__ __align__(16) __bf16 As[128 * 32];
    __shared__ __align__(16) __bf16 Bs[128 * 32];
    __shared__ int tokrow[128];

    const int tid = threadIdx.x;
    const int wv = tid >> 6, lane = tid & 63;

    if (tid < 128) {
        const int gr = m0 + tid;
        const int grc = min(gr, nrows - 1);
        tokrow[tid] = perm[base + grc] >> 2;
    }
    __syncthreads();

    const int ca0 = wv * 64 + lane, ca1 = 256 + wv * 64 + lane;
    const int ra0 = ca0 >> 2, ka0 = (ca0 & 3) ^ (ra0 & 3);
    const int ra1 = ca1 >> 2, ka1 = (ca1 & 3) ^ (ra1 & 3);
    const __bf16* a_src0 = h + (size_t)(base + min(m0 + ra0, nrows - 1)) * I_DIM + ka0 * 8;
    const __bf16* a_src1 = h + (size_t)(base + min(m0 + ra1, nrows - 1)) * I_DIM + ka1 * 8;
    const size_t wbase = (size_t)e * I_DIM * D_DIM;
    const __bf16* b_src0 = wdnT + wbase + (size_t)(c0 + ra0) * I_DIM + ka0 * 8;
    const __bf16* b_src1 = wdnT + wbase + (size_t)(c0 + ra1) * I_DIM + ka1 * 8;
    __bf16* a_dst0 = As + wv * 512;
    __bf16* a_dst1 = As + 2048 + wv * 512;
    __bf16* b_dst0 = Bs + wv * 512;
    __bf16* b_dst1 = Bs + 2048 + wv * 512;

    const int wr = wv >> 1, wc = wv & 1;
    int a_off[4], b_off[4];
#pragma unroll
    for (int m = 0; m < 4; ++m) {
        const int row = wr * 64 + m * 16 + (lane & 15);
        a_off[m] = row * 32 + (((lane >> 4) ^ (row & 3)) << 3);
        const int col = wc * 64 + m * 16 + (lane & 15);
        b_off[m] = col * 32 + (((lane >> 4) ^ (col & 3)) << 3);
    }

    f32x4 acc[4][4] = {};
    for (int d0 = 0; d0 < I_DIM; d0 += 32) {
        gload_lds16(a_src0 + d0, a_dst0);
        gload_lds16(a_src1 + d0, a_dst1);
        gload_lds16(b_src0 + d0, b_dst0);
        gload_lds16(b_src1 + d0, b_dst1);
        __syncthreads();
        bf16x8 af[4], bf[4];
#pragma unroll
        for (int m = 0; m < 4; ++m) {
            af[m] = *reinterpret_cast<const bf16x8*>(&As[a_off[m]]);
            bf[m] = *reinterpret_cast<const bf16x8*>(&Bs[b_off[m]]);
        }
#pragma unroll
        for (int m = 0; m < 4; ++m)
#pragma unroll
            for (int n = 0; n < 4; ++n)
                acc[m][n] = __builtin_amdgcn_mfma_f32_16x16x32_bf16(af[m], bf[n], acc[m][n], 0, 0, 0);
        __syncthreads();
    }

#pragma unroll
    for (int m = 0; m < 4; ++m)
#pragma unroll
        for (int j = 0; j < 4; ++j) {
            const int lr = wr * 64 + m * 16 + (lane >> 4) * 4 + j;
            const int gr = m0 + lr;
            if (gr < nrows) {
                const int tok = tokrow[lr];
#pragma unroll
                for (int n = 0; n < 4; ++n) {
                    const int col = c0 + wc * 64 + n * 16 + (lane & 15);
                    atomicAdd(&y[(size_t)tok * D_DIM + col], acc[m][n][j]);
                }
            }
        }
}

// ================= fallback fp32 path (round-0, proven) ======================
__global__ __launch_bounds__(256) void gate_gemm_kernel(
    const float* __restrict__ x, const float* __restrict__ wgu,
    const int* __restrict__ offsets, const int* __restrict__ perm,
    const float* __restrict__ sel_w, float* __restrict__ h)
{
    const int e = blockIdx.z;
    const int base = offsets[e];
    const int nrows = offsets[e + 1] - base;
    const int m0 = blockIdx.y * 64;
    if (m0 >= nrows) return;
    const int c0 = blockIdx.x * 64;
    const int tid = threadIdx.x;
    __shared__ float As[16][64];
    __shared__ float Bg[16][64];
    __shared__ float Bu[16][64];
    const int lrow = tid >> 2;
    const int c4 = (tid & 3) * 4;
    const int grow = m0 + lrow;
    const bool arow_ok = (grow < nrows);
    const float* xrow = nullptr;
    if (arow_ok) {
        const int pv = perm[base + grow];
        xrow = x + (size_t)(pv >> 2) * D_DIM;
    }
    const int bcol = tid & 63;
    const int brow0 = tid >> 6;
    const float* wbase = wgu + (size_t)e * D_DIM * TWOI;
    const int tx = tid & 15, ty = tid >> 4;
    float accg[4][4] = {}, accu[4][4] = {};
    for (int d0 = 0; d0 < D_DIM; d0 += 16) {
        float4 av = make_float4(0.f, 0.f, 0.f, 0.f);
        if (arow_ok) av = *reinterpret_cast<const float4*>(xrow + d0 + c4);
        As[c4 + 0][lrow] = av.x; As[c4 + 1][lrow] = av.y;
        As[c4 + 2][lrow] = av.z; As[c4 + 3][lrow] = av.w;
#pragma unroll
        for (int r = 0; r < 4; ++r) {
            const int dd = d0 + brow0 + r * 4;
            const float* wr = wbase + (size_t)dd * TWOI;
            Bg[brow0 + r * 4][bcol] = wr[c0 + bcol];
            Bu[brow0 + r * 4][bcol] = wr[c0 + 512 + bcol];
        }
        __syncthreads();
#pragma unroll
        for (int kk = 0; kk < 16; ++kk) {
            const float4 a  = *reinterpret_cast<const float4*>(&As[kk][ty * 4]);
            const float4 bg = *reinterpret_cast<const float4*>(&Bg[kk][tx * 4]);
            const float4 bu = *reinterpret_cast<const float4*>(&Bu[kk][tx * 4]);
            const float aa[4] = { a.x, a.y, a.z, a.w };
            const float gg[4] = { bg.x, bg.y, bg.z, bg.w };
            const float uu[4] = { bu.x, bu.y, bu.z, bu.w };
#pragma unroll
            for (int i2 = 0; i2 < 4; ++i2)
#pragma unroll
                for (int j = 0; j < 4; ++j) {
                    accg[i2][j] += aa[i2] * gg[j];
                    accu[i2][j] += aa[i2] * uu[j];
                }
        }
        __syncthreads();
    }
#pragma unroll
    for (int i2 = 0; i2 < 4; ++i2) {
        const int r = ty * 4 + i2;
        const int gr = m0 + r;
        if (gr < nrows) {
            const int pv = perm[base + gr];
            const float wgt = sel_w[pv];
            float* hrow = h + (size_t)(base + gr) * I_DIM + c0;
#pragma unroll
            for (int j = 0; j < 4; ++j) {
                const float g = accg[i2][j];
                const float u = accu[i2][j];
                const float s = g / (1.f + expf(-g));
                hrow[tx * 4 + j] = s * u * wgt;
            }
        }
    }
}

__global__ __launch_bounds__(256) void down_gemm_kernel(
    const float* __restrict__ h, const float* __restrict__ wdn,
    const int* __restrict__ offsets, const int* __restrict__ perm,
    float* __restrict__ y)
{
    const int e = blockIdx.z;
    const int base = offsets[e];
    const int nrows = offsets[e + 1] - base;
    const int m0 = blockIdx.y * 64;
    if (m0 >= nrows) return;
    const int c0 = blockIdx.x * 64;
    const int tid = threadIdx.x;
    __shared__ float As[16][64];
    __shared__ float Bs[16][64];
    const int lrow = tid >> 2;
    const int c4 = (tid & 3) * 4;
    const int grow = m0 + lrow;
    const bool arow_ok = (grow < nrows);
    const float* hrow = arow_ok ? (h + (size_t)(base + grow) * I_DIM) : nullptr;
    const int bcol = tid & 63;
    const int brow0 = tid >> 6;
    const float* wbase = wdn + (size_t)e * I_DIM * D_DIM;
    const int tx = tid & 15, ty = tid >> 4;
    float acc[4][4] = {};
    for (int d0 = 0; d0 < I_DIM; d0 += 16) {
        float4 av = make_float4(0.f, 0.f, 0.f, 0.f);
        if (arow_ok) av = *reinterpret_cast<const float4*>(hrow + d0 + c4);
        As[c4 + 0][lrow] = av.x; As[c4 + 1][lrow] = av.y;
        As[c4 + 2][lrow] = av.z; As[c4 + 3][lrow] = av.w;
#pragma unroll
        for (int r = 0; r < 4; ++r) {
            const int dd = d0 + brow0 + r * 4;
            Bs[brow0 + r * 4][bcol] = wbase[(size_t)dd * D_DIM + c0 + bcol];
        }
        __syncthreads();
#pragma unroll
        for (int kk = 0; kk < 16; ++kk) {
            const float4 a = *reinterpret_cast<const float4*>(&As[kk][ty * 4]);
            const float4 b = *reinterpret_cast<const float4*>(&Bs[kk][tx * 4]);
            const float aa[4] = { a.x, a.y, a.z, a.w };
            const float bb[4] = { b.x, b.y, b.z, b.w };
#pragma unroll
            for (int i2 = 0; i2 < 4; ++i2)
#pragma unroll
                for (int j = 0; j < 4; ++j)
                    acc[i2][j] += aa[i2] * bb[j];
        }
        __syncthreads();
    }
#pragma unroll
    for (int i2 = 0; i2 < 4; ++i2) {
        const int r = ty * 4 + i2;
        const int gr = m0 + r;
        if (gr < nrows) {
            const int pv = perm[base + gr];
            const int t = pv >> 2;
            float* yrow = y + (size_t)t * D_DIM + c0;
#pragma unroll
            for (int j = 0; j < 4; ++j)
                atomicAdd(&yrow[tx * 4 + j], acc[i2][j]);
        }
    }
}

// ---------------- launch -----------------------------------------------------
extern "C" void kernel_launch(void* const* d_in, const int* in_sizes, int n_in,
                              void* d_out, int out_size, void* d_ws, size_t ws_size,
                              hipStream_t stream)
{
    const float* x      = (const float*)d_in[0];
    const float* router = (const float*)d_in[1];
    const float* rbias  = (const float*)d_in[2];
    const float* wgu    = (const float*)d_in[3];
    const float* wdn    = (const float*)d_in[4];
    float* out = (float*)d_out;

    char* ws = (char*)d_ws;
    int*   sel_idx = (int*)(ws);                    // 32 KB
    float* sel_w   = (float*)(ws + 32768);          // 32 KB
    int*   perm    = (int*)(ws + 65536);            // 32 KB
    int*   inv     = (int*)(ws + 98304);            // 32 KB
    int*   counts  = (int*)(ws + 131072);
    int*   offsets = (int*)(ws + 131328);
    int*   cursor  = (int*)(ws + 131584);
    __bf16* xb     = (__bf16*)(ws + 262144);        // 4 MB
    __bf16* hb     = (__bf16*)(ws + 4456448);       // 8 MB
    __bf16* wguT   = (__bf16*)(ws + 12845056);      // 32 MB
    __bf16* wdnT   = (__bf16*)(ws + 46399488);      // 16 MB -> 63176704
    float* yp      = (float*)(ws + 63242240);       // 32 MB -> 96796672
    float* hf      = (float*)(ws + 262144);         // fallback fp32 h (16.8 MB)

    const bool fast = (ws_size >= 96796672ULL);
    const bool mid  = (ws_size >= 63242240ULL);

    hipMemsetAsync(counts, 0, 64, stream);
    if (!fast)
        hipMemsetAsync(out, 0, (size_t)T_TOK * D_DIM * sizeof(float), stream);

    router_lds_kernel<<<T_TOK / RT_TOK, 256, 0, stream>>>(x, router, rbias, sel_idx, sel_w, counts);
    scan_stats_kernel<<<1, 64, 0, stream>>>(counts, offsets, cursor,
                                            out + (size_t)T_TOK * D_DIM);
    scatter_kernel<<<(T_TOK * K_TOP + 255) / 256, 256, 0, stream>>>(sel_idx, cursor, perm, inv);

    if (mid) {
        convert_x_kernel<<<T_TOK * D_DIM / 8 / 256, 256, 0, stream>>>(x, xb);
        transpose_w_kernel<<<dim3(TWOI / 32, D_DIM / 32, E_NUM), 256, 0, stream>>>(wgu, wguT, D_DIM, TWOI);
        transpose_w_kernel<<<dim3(D_DIM / 32, I_DIM / 32, E_NUM), 256, 0, stream>>>(wdn, wdnT, I_DIM, D_DIM);
        gate_mfma_kernel<<<dim3(16, 16, E_NUM), 256, 0, stream>>>(xb, wguT, offsets, perm, sel_w, hb);
        if (fast) {
            down_mfma_p_kernel<<<dim3(16, 16, E_NUM), 256, 0, stream>>>(hb, wdnT, offsets, yp);
            combine_kernel<<<T_TOK, 256, 0, stream>>>(yp, inv, out);
        } else {
            down_mfma_kernel<<<dim3(8, 16, E_NUM), 256, 0, stream>>>(hb, wdnT, offsets, perm, out);
        }
    } else {
        gate_gemm_kernel<<<dim3(8, 32, E_NUM), 256, 0, stream>>>(x, wgu, offsets, perm, sel_w, hf);
        down_gemm_kernel<<<dim3(16, 32, E_NUM), 256, 0, stream>>>(hf, wdn, offsets, perm, out);
    }
}

// Round 9
// 265.517 us; speedup vs baseline: 1.3547x; 1.0608x over previous
//
#include <hip/hip_runtime.h>
#include <hip/hip_bf16.h>
#include <cstdint>

#define T_TOK 2048
#define D_DIM 1024
#define E_NUM 16
#define K_TOP 4
#define I_DIM 512
#define TWOI  1024
#define RT_TOK 16
#define XST   258

typedef __bf16 bf16x8 __attribute__((ext_vector_type(8)));
typedef __bf16 bf16x4 __attribute__((ext_vector_type(4)));
typedef float  f32x4  __attribute__((ext_vector_type(4)));

__device__ __forceinline__ void gload_lds16(const void* g, void* l) {
    __builtin_amdgcn_global_load_lds(
        (const __attribute__((address_space(1))) void*)(uintptr_t)(g),
        (__attribute__((address_space(3))) void*)(uintptr_t)(l),
        16, 0, 0);
}

// ---------------- router: LDS-staged, fully coalesced, fp32 exact ------------
__global__ __launch_bounds__(256) void router_lds_kernel(
    const float* __restrict__ x, const float* __restrict__ router,
    const float* __restrict__ rbias,
    int* __restrict__ sel_idx, float* __restrict__ sel_w, int* __restrict__ counts)
{
    __shared__ float rl[256 * 16];
    __shared__ float xs[RT_TOK * XST];
    __shared__ float red2[4 * RT_TOK * 16];
    __shared__ float lgs[RT_TOK * 16];

    const int tid = threadIdx.x;
    const int t0 = blockIdx.x * RT_TOK;
    const int t = tid & 15, q = tid >> 4;
    const int lane = tid & 63, wv = tid >> 6;

    float acc[E_NUM];
#pragma unroll
    for (int e = 0; e < E_NUM; ++e) acc[e] = 0.f;

    for (int c = 0; c < 4; ++c) {
        {
            const float* rg = router + (size_t)(c * 256 + tid) * E_NUM;
            const int rot = (tid >> 4) & 3;
#pragma unroll
            for (int g = 0; g < 4; ++g) {
                const f32x4 v = *reinterpret_cast<const f32x4*>(rg + g * 4);
                *reinterpret_cast<f32x4*>(&rl[tid * 16 + ((g + rot) & 3) * 4]) = v;
            }
        }
        {
            const int r = tid >> 4, cb = (tid & 15) * 16;
            const float* xg = x + (size_t)(t0 + r) * D_DIM + c * 256 + cb;
            float v[16];
#pragma unroll
            for (int g = 0; g < 4; ++g) {
                const f32x4 vv = *reinterpret_cast<const f32x4*>(xg + g * 4);
                v[g*4+0] = vv[0]; v[g*4+1] = vv[1]; v[g*4+2] = vv[2]; v[g*4+3] = vv[3];
            }
            float* xd = &xs[r * XST + cb];
#pragma unroll
            for (int i = 0; i < 8; ++i) {
                float2 w; w.x = v[i*2]; w.y = v[i*2+1];
                *reinterpret_cast<float2*>(xd + i * 2) = w;
            }
        }
        __syncthreads();
#pragma unroll
        for (int j = 0; j < 16; ++j) {
            const int dl = q * 16 + j;
            const float xv = xs[t * XST + dl];
#pragma unroll
            for (int g = 0; g < 4; ++g) {
                const f32x4 rv = *reinterpret_cast<const f32x4*>(
                    &rl[dl * 16 + ((g + q) & 3) * 4]);
#pragma unroll
                for (int i = 0; i < 4; ++i)
                    acc[g * 4 + i] += xv * rv[i];
            }
        }
        __syncthreads();
    }

#pragma unroll
    for (int e = 0; e < E_NUM; ++e) {
        acc[e] += __shfl_xor(acc[e], 16);
        acc[e] += __shfl_xor(acc[e], 32);
    }
    if (lane < 16) {
#pragma unroll
        for (int g = 0; g < 4; ++g) {
            f32x4 v; v[0] = acc[g*4]; v[1] = acc[g*4+1]; v[2] = acc[g*4+2]; v[3] = acc[g*4+3];
            *reinterpret_cast<f32x4*>(&red2[(wv * RT_TOK + lane) * 16 + g * 4]) = v;
        }
    }
    __syncthreads();
    {
        const int tt = tid >> 4, ee = tid & 15;
        const float s = red2[(0 * RT_TOK + tt) * 16 + ee]
                      + red2[(1 * RT_TOK + tt) * 16 + ee]
                      + red2[(2 * RT_TOK + tt) * 16 + ee]
                      + red2[(3 * RT_TOK + tt) * 16 + ee];
        lgs[tt * 16 + ee] = s;
    }
    __syncthreads();
    if (tid < RT_TOK) {
        const int tok = t0 + tid;
        float lg[E_NUM], bi[E_NUM];
#pragma unroll
        for (int j = 0; j < E_NUM; ++j) { lg[j] = lgs[tid * 16 + j]; bi[j] = lg[j] + rbias[j]; }
        bool used[E_NUM];
#pragma unroll
        for (int j = 0; j < E_NUM; ++j) used[j] = false;
        int selv[K_TOP]; float wvv[K_TOP]; float wsum = 0.f;
#pragma unroll
        for (int k = 0; k < K_TOP; ++k) {
            float best = -1e30f; int bidx = 0;
#pragma unroll
            for (int j = 0; j < E_NUM; ++j)
                if (!used[j] && bi[j] > best) { best = bi[j]; bidx = j; }
            used[bidx] = true; selv[k] = bidx;
            const float s = 1.f / (1.f + expf(-lg[bidx]));
            wvv[k] = s; wsum += s;
        }
#pragma unroll
        for (int k = 0; k < K_TOP; ++k) {
            sel_idx[tok * K_TOP + k] = selv[k];
            sel_w[tok * K_TOP + k] = wvv[k] / wsum;
            atomicAdd(&counts[selv[k]], 1);
        }
    }
}

// ---------------- prefix scan + counts/entropy -----------------
__global__ void scan_stats_kernel(const int* __restrict__ counts,
                                  int* __restrict__ offsets, int* __restrict__ cursor,
                                  float* __restrict__ out_tail)
{
    if (threadIdx.x == 0 && blockIdx.x == 0) {
        int off = 0; float tot = 0.f;
        for (int e = 0; e < E_NUM; ++e) {
            offsets[e] = off; cursor[e] = off; off += counts[e];
            tot += (float)counts[e];
        }
        offsets[E_NUM] = off;
        const float total = fmaxf(tot, 1.f);
        float ent = 0.f;
        for (int e = 0; e < E_NUM; ++e) {
            const float c = (float)counts[e];
            const float frac = c / total;
            ent -= frac * logf(frac + 1e-6f);
            out_tail[e] = c;
        }
        out_tail[E_NUM] = ent;
    }
}

// ---------------- expert-grouped permutation (+ inverse) -----------------
__global__ void scatter_kernel(const int* __restrict__ sel_idx,
                               int* __restrict__ cursor, int* __restrict__ perm,
                               int* __restrict__ inv)
{
    const int i = blockIdx.x * 256 + threadIdx.x;
    if (i >= T_TOK * K_TOP) return;
    const int e = sel_idx[i];
    const int pos = atomicAdd(&cursor[e], 1);
    perm[pos] = i;
    inv[i] = pos;
}

// ---------------- x fp32 -> bf16 -----------------
__global__ __launch_bounds__(256) void convert_x_kernel(
    const float* __restrict__ x, __bf16* __restrict__ xb)
{
    const int i = blockIdx.x * 256 + threadIdx.x;
    const float4 a = reinterpret_cast<const float4*>(x)[i * 2];
    const float4 b = reinterpret_cast<const float4*>(x)[i * 2 + 1];
    bf16x8 o;
    o[0] = (__bf16)a.x; o[1] = (__bf16)a.y; o[2] = (__bf16)a.z; o[3] = (__bf16)a.w;
    o[4] = (__bf16)b.x; o[5] = (__bf16)b.y; o[6] = (__bf16)b.z; o[7] = (__bf16)b.w;
    reinterpret_cast<bf16x8*>(xb)[i] = o;
}

// ---------------- weight transpose fp32 [e][R][C] -> bf16 [e][C][R] ----------
__global__ __launch_bounds__(256) void transpose_w_kernel(
    const float* __restrict__ in, __bf16* __restrict__ out, int R, int C)
{
    const int e = blockIdx.z;
    const int r0 = blockIdx.y * 32, c0 = blockIdx.x * 32;
    const int tid = threadIdx.x;
    const int r = tid >> 3, c4 = (tid & 7) * 4;
    __shared__ float lds[32][33];
    const float4 v = *reinterpret_cast<const float4*>(
        in + (size_t)e * R * C + (size_t)(r0 + r) * C + c0 + c4);
    lds[c4 + 0][r] = v.x; lds[c4 + 1][r] = v.y;
    lds[c4 + 2][r] = v.z; lds[c4 + 3][r] = v.w;
    __syncthreads();
    bf16x4 o;
    o[0] = (__bf16)lds[r][c4 + 0]; o[1] = (__bf16)lds[r][c4 + 1];
    o[2] = (__bf16)lds[r][c4 + 2]; o[3] = (__bf16)lds[r][c4 + 3];
    *reinterpret_cast<bf16x4*>(out + (size_t)e * R * C + (size_t)(c0 + r) * R + r0 + c4) = o;
}

// ---------------- gate/up MFMA GEMM: BK=64, 128 rows x (32 g + 32 u) ---------
__global__ __launch_bounds__(256) void gate_mfma_kernel(
    const __bf16* __restrict__ xb, const __bf16* __restrict__ wguT,
    const int* __restrict__ offsets, const int* __restrict__ perm,
    const float* __restrict__ sel_w, __bf16* __restrict__ h)
{
    const int e = blockIdx.z;
    const int base = offsets[e];
    const int nrows = offsets[e + 1] - base;
    const int m0 = blockIdx.y * 128;
    if (m0 >= nrows) return;
    const int c0 = blockIdx.x * 32;

    __shared__ __align__(16) __bf16 As[128 * 64];   // 16 KB
    __shared__ __align__(16) __bf16 Bg[32 * 64];    // 4 KB
    __shared__ __align__(16) __bf16 Bu[32 * 64];    // 4 KB
    __shared__ int   tokrow[128];
    __shared__ float wrow[128];

    const int tid = threadIdx.x;
    const int wv = tid >> 6, lane = tid & 63;

    if (tid < 128) {
        const int gr = m0 + tid;
        const int grc = min(gr, nrows - 1);
        const int pv = perm[base + grc];
        tokrow[tid] = pv >> 2;
        wrow[tid] = (gr < nrows) ? sel_w[pv] : 0.f;
    }
    __syncthreads();

    // A staging: 1024 chunks (128 rows x 8 kc of 16B), 4/thread.
    // Pre-swizzled GLOBAL source (kc ^= row&7), linear LDS dest (rule #21).
    const __bf16* a_srcp[4];
    __bf16* a_dst[4];
#pragma unroll
    for (int j = 0; j < 4; ++j) {
        const int ca = j * 256 + tid;
        const int ra = ca >> 3;
        const int kc = (ca & 7) ^ (ra & 7);
        a_srcp[j] = xb + (size_t)tokrow[ra] * D_DIM + kc * 8;
        a_dst[j] = As + j * 2048 + wv * 512;
    }
    // B staging: 1 chunk each for Bg, Bu per thread (32 rows x 8 kc each)
    const int rb = tid >> 3;
    const int kcb = (tid & 7) ^ (rb & 7);
    const size_t wbase = (size_t)e * D_DIM * TWOI;
    const __bf16* bg_src = wguT + wbase + (size_t)(c0 + rb) * D_DIM + kcb * 8;
    const __bf16* bu_src = wguT + wbase + (size_t)(c0 + 512 + rb) * D_DIM + kcb * 8;
    __bf16* bg_dst = Bg + wv * 512;
    __bf16* bu_dst = Bu + wv * 512;

    const int wr = wv >> 1, wc = wv & 1;
    int a_off[4][2];
#pragma unroll
    for (int m = 0; m < 4; ++m)
#pragma unroll
        for (int kk = 0; kk < 2; ++kk) {
            const int row = wr * 64 + m * 16 + (lane & 15);
            const int c = kk * 4 + (lane >> 4);
            a_off[m][kk] = row * 64 + ((c ^ (row & 7)) << 3);
        }
    int b_off[2];
    {
        const int col = wc * 16 + (lane & 15);
#pragma unroll
        for (int kk = 0; kk < 2; ++kk) {
            const int c = kk * 4 + (lane >> 4);
            b_off[kk] = col * 64 + ((c ^ (col & 7)) << 3);
        }
    }

    f32x4 accg[4] = {}; f32x4 accu[4] = {};
    for (int d0 = 0; d0 < D_DIM; d0 += 64) {
#pragma unroll
        for (int j = 0; j < 4; ++j) gload_lds16(a_srcp[j] + d0, a_dst[j]);
        gload_lds16(bg_src + d0, bg_dst);
        gload_lds16(bu_src + d0, bu_dst);
        __syncthreads();
#pragma unroll
        for (int kk = 0; kk < 2; ++kk) {
            bf16x8 af[4];
#pragma unroll
            for (int m = 0; m < 4; ++m)
                af[m] = *reinterpret_cast<const bf16x8*>(&As[a_off[m][kk]]);
            const bf16x8 bgf = *reinterpret_cast<const bf16x8*>(&Bg[b_off[kk]]);
            const bf16x8 buf = *reinterpret_cast<const bf16x8*>(&Bu[b_off[kk]]);
#pragma unroll
            for (int m = 0; m < 4; ++m) {
                accg[m] = __builtin_amdgcn_mfma_f32_16x16x32_bf16(af[m], bgf, accg[m], 0, 0, 0);
                accu[m] = __builtin_amdgcn_mfma_f32_16x16x32_bf16(af[m], buf, accu[m], 0, 0, 0);
            }
        }
        __syncthreads();
    }

    const int ocol = c0 + wc * 16 + (lane & 15);
#pragma unroll
    for (int m = 0; m < 4; ++m)
#pragma unroll
        for (int j = 0; j < 4; ++j) {
            const int lr = wr * 64 + m * 16 + (lane >> 4) * 4 + j;
            const int gr = m0 + lr;
            if (gr < nrows) {
                const float g = accg[m][j];
                const float u = accu[m][j];
                const float s = g / (1.f + expf(-g));
                h[(size_t)(base + gr) * I_DIM + ocol] = (__bf16)(s * u * wrow[lr]);
            }
        }
}

// ---------------- down MFMA GEMM: BK=64, 128 rows x 64 cols, partial out -----
__global__ __launch_bounds__(256) void down_mfma_p_kernel(
    const __bf16* __restrict__ h, const __bf16* __restrict__ wdnT,
    const int* __restrict__ offsets, float* __restrict__ yp)
{
    const int e = blockIdx.z;
    const int base = offsets[e];
    const int nrows = offsets[e + 1] - base;
    const int m0 = blockIdx.y * 128;
    if (m0 >= nrows) return;
    const int c0 = blockIdx.x * 64;

    __shared__ __align__(16) __bf16 As[128 * 64];   // 16 KB
    __shared__ __align__(16) __bf16 Bs[64 * 64];    // 8 KB

    const int tid = threadIdx.x;
    const int wv = tid >> 6, lane = tid & 63;

    const __bf16* a_srcp[4];
    __bf16* a_dst[4];
#pragma unroll
    for (int j = 0; j < 4; ++j) {
        const int ca = j * 256 + tid;
        const int ra = ca >> 3;
        const int kc = (ca & 7) ^ (ra & 7);
        a_srcp[j] = h + (size_t)(base + min(m0 + ra, nrows - 1)) * I_DIM + kc * 8;
        a_dst[j] = As + j * 2048 + wv * 512;
    }
    const size_t wbase = (size_t)e * I_DIM * D_DIM;
    const __bf16* b_srcp[2];
    __bf16* b_dst[2];
#pragma unroll
    for (int j = 0; j < 2; ++j) {
        const int cb = j * 256 + tid;
        const int rbn = cb >> 3;
        const int kc = (cb & 7) ^ (rbn & 7);
        b_srcp[j] = wdnT + wbase + (size_t)(c0 + rbn) * I_DIM + kc * 8;
        b_dst[j] = Bs + j * 2048 + wv * 512;
    }

    const int wr = wv >> 1, wc = wv & 1;
    int a_off[4][2], b_off[2][2];
#pragma unroll
    for (int m = 0; m < 4; ++m)
#pragma unroll
        for (int kk = 0; kk < 2; ++kk) {
            const int row = wr * 64 + m * 16 + (lane & 15);
            const int c = kk * 4 + (lane >> 4);
            a_off[m][kk] = row * 64 + ((c ^ (row & 7)) << 3);
        }
#pragma unroll
    for (int n = 0; n < 2; ++n)
#pragma unroll
        for (int kk = 0; kk < 2; ++kk) {
            const int col = wc * 32 + n * 16 + (lane & 15);
            const int c = kk * 4 + (lane >> 4);
            b_off[n][kk] = col * 64 + ((c ^ (col & 7)) << 3);
        }

    f32x4 acc[4][2] = {};
    for (int d0 = 0; d0 < I_DIM; d0 += 64) {
#pragma unroll
        for (int j = 0; j < 4; ++j) gload_lds16(a_srcp[j] + d0, a_dst[j]);
#pragma unroll
        for (int j = 0; j < 2; ++j) gload_lds16(b_srcp[j] + d0, b_dst[j]);
        __syncthreads();
#pragma unroll
        for (int kk = 0; kk < 2; ++kk) {
            bf16x8 af[4], bf[2];
#pragma unroll
            for (int m = 0; m < 4; ++m)
                af[m] = *reinterpret_cast<const bf16x8*>(&As[a_off[m][kk]]);
#pragma unroll
            for (int n = 0; n < 2; ++n)
                bf[n] = *reinterpret_cast<const bf16x8*>(&Bs[b_off[n][kk]]);
#pragma unroll
            for (int m = 0; m < 4; ++m)
#pragma unroll
                for (int n = 0; n < 2; ++n)
                    acc[m][n] = __builtin_amdgcn_mfma_f32_16x16x32_bf16(af[m], bf[n], acc[m][n], 0, 0, 0);
        }
        __syncthreads();
    }

#pragma unroll
    for (int m = 0; m < 4; ++m)
#pragma unroll
        for (int j = 0; j < 4; ++j) {
            const int lr = wr * 64 + m * 16 + (lane >> 4) * 4 + j;
            const int gr = m0 + lr;
            if (gr < nrows) {
#pragma unroll
                for (int n = 0; n < 2; ++n) {
                    const int col = c0 + wc * 32 + n * 16 + (lane & 15);
                    yp[(size_t)(base + gr) * D_DIM + col] = acc[m][n][j];
                }
            }
        }
}

// ---------------- combine: y[t] = sum_k yp[inv[t*4+k]] -----------------------
__global__ __launch_bounds__(256) void combine_kernel(
    const float* __restrict__ yp, const int* __restrict__ inv, float* __restrict__ y)
{
    const int t = blockIdx.x, tid = threadIdx.x;
    const int r0 = inv[t * 4 + 0], r1 = inv[t * 4 + 1];
    const int r2 = inv[t * 4 + 2], r3 = inv[t * 4 + 3];
    const float4 a = reinterpret_cast<const float4*>(yp + (size_t)r0 * D_DIM)[tid];
    const float4 b = reinterpret_cast<const float4*>(yp + (size_t)r1 * D_DIM)[tid];
    const float4 c = reinterpret_cast<const float4*>(yp + (size_t)r2 * D_DIM)[tid];
    const float4 d = reinterpret_cast<const float4*>(yp + (size_t)r3 * D_DIM)[tid];
    float4 s;
    s.x = (a.x + b.x) + (c.x + d.x);
    s.y = (a.y + b.y) + (c.y + d.y);
    s.z = (a.z + b.z) + (c.z + d.z);
    s.w = (a.w + b.w) + (c.w + d.w);
    reinterpret_cast<float4*>(y + (size_t)t * D_DIM)[tid] = s;
}

// ---------------- down MFMA GEMM (mid tier): 128x128, atomic scatter ---------
__global__ __launch_bounds__(256) void down_mfma_kernel(
    const __bf16* __restrict__ h, const __bf16* __restrict__ wdnT,
    const int* __restrict__ offsets, const int* __restrict__ perm,
    float* __restrict__ y)
{
    const int e = blockIdx.z;
    const int base = offsets[e];
    const int nrows = offsets[e + 1] - base;
    const int m0 = blockIdx.y * 128;
    if (m0 >= nrows) return;
    const int c0 = blockIdx.x * 128;

    __shared__ __align__(16) __bf16 As[128 * 32];
    __shared__ __align__(16) __bf16 Bs[128 * 32];
    __shared__ int tokrow[128];

    const int tid = threadIdx.x;
    const int wv = tid >> 6, lane = tid & 63;

    if (tid < 128) {
        const int gr = m0 + tid;
        const int grc = min(gr, nrows - 1);
        tokrow[tid] = perm[base + grc] >> 2;
    }
    __syncthreads();

    const int ca0 = wv * 64 + lane, ca1 = 256 + wv * 64 + lane;
    const int ra0 = ca0 >> 2, ka0 = (ca0 & 3) ^ (ra0 & 3);
    const int ra1 = ca1 >> 2, ka1 = (ca1 & 3) ^ (ra1 & 3);
    const __bf16* a_src0 = h + (size_t)(base + min(m0 + ra0, nrows - 1)) * I_DIM + ka0 * 8;
    const __bf16* a_src1 = h + (size_t)(base + min(m0 + ra1, nrows - 1)) * I_DIM + ka1 * 8;
    const size_t wbase = (size_t)e * I_DIM * D_DIM;
    const __bf16* b_src0 = wdnT + wbase + (size_t)(c0 + ra0) * I_DIM + ka0 * 8;
    const __bf16* b_src1 = wdnT + wbase + (size_t)(c0 + ra1) * I_DIM + ka1 * 8;
    __bf16* a_dst0 = As + wv * 512;
    __bf16* a_dst1 = As + 2048 + wv * 512;
    __bf16* b_dst0 = Bs + wv * 512;
    __bf16* b_dst1 = Bs + 2048 + wv * 512;

    const int wr = wv >> 1, wc = wv & 1;
    int a_off[4], b_off[4];
#pragma unroll
    for (int m = 0; m < 4; ++m) {
        const int row = wr * 64 + m * 16 + (lane & 15);
        a_off[m] = row * 32 + (((lane >> 4) ^ (row & 3)) << 3);
        const int col = wc * 64 + m * 16 + (lane & 15);
        b_off[m] = col * 32 + (((lane >> 4) ^ (col & 3)) << 3);
    }

    f32x4 acc[4][4] = {};
    for (int d0 = 0; d0 < I_DIM; d0 += 32) {
        gload_lds16(a_src0 + d0, a_dst0);
        gload_lds16(a_src1 + d0, a_dst1);
        gload_lds16(b_src0 + d0, b_dst0);
        gload_lds16(b_src1 + d0, b_dst1);
        __syncthreads();
        bf16x8 af[4], bf[4];
#pragma unroll
        for (int m = 0; m < 4; ++m) {
            af[m] = *reinterpret_cast<const bf16x8*>(&As[a_off[m]]);
            bf[m] = *reinterpret_cast<const bf16x8*>(&Bs[b_off[m]]);
        }
#pragma unroll
        for (int m = 0; m < 4; ++m)
#pragma unroll
            for (int n = 0; n < 4; ++n)
                acc[m][n] = __builtin_amdgcn_mfma_f32_16x16x32_bf16(af[m], bf[n], acc[m][n], 0, 0, 0);
        __syncthreads();
    }

#pragma unroll
    for (int m = 0; m < 4; ++m)
#pragma unroll
        for (int j = 0; j < 4; ++j) {
            const int lr = wr * 64 + m * 16 + (lane >> 4) * 4 + j;
            const int gr = m0 + lr;
            if (gr < nrows) {
                const int tok = tokrow[lr];
#pragma unroll
                for (int n = 0; n < 4; ++n) {
                    const int col = c0 + wc * 64 + n * 16 + (lane & 15);
                    atomicAdd(&y[(size_t)tok * D_DIM + col], acc[m][n][j]);
                }
            }
        }
}

// ================= fallback fp32 path (round-0, proven) ======================
__global__ __launch_bounds__(256) void gate_gemm_kernel(
    const float* __restrict__ x, const float* __restrict__ wgu,
    const int* __restrict__ offsets, const int* __restrict__ perm,
    const float* __restrict__ sel_w, float* __restrict__ h)
{
    const int e = blockIdx.z;
    const int base = offsets[e];
    const int nrows = offsets[e + 1] - base;
    const int m0 = blockIdx.y * 64;
    if (m0 >= nrows) return;
    const int c0 = blockIdx.x * 64;
    const int tid = threadIdx.x;
    __shared__ float As[16][64];
    __shared__ float Bg[16][64];
    __shared__ float Bu[16][64];
    const int lrow = tid >> 2;
    const int c4 = (tid & 3) * 4;
    const int grow = m0 + lrow;
    const bool arow_ok = (grow < nrows);
    const float* xrow = nullptr;
    if (arow_ok) {
        const int pv = perm[base + grow];
        xrow = x + (size_t)(pv >> 2) * D_DIM;
    }
    const int bcol = tid & 63;
    const int brow0 = tid >> 6;
    const float* wbase = wgu + (size_t)e * D_DIM * TWOI;
    const int tx = tid & 15, ty = tid >> 4;
    float accg[4][4] = {}, accu[4][4] = {};
    for (int d0 = 0; d0 < D_DIM; d0 += 16) {
        float4 av = make_float4(0.f, 0.f, 0.f, 0.f);
        if (arow_ok) av = *reinterpret_cast<const float4*>(xrow + d0 + c4);
        As[c4 + 0][lrow] = av.x; As[c4 + 1][lrow] = av.y;
        As[c4 + 2][lrow] = av.z; As[c4 + 3][lrow] = av.w;
#pragma unroll
        for (int r = 0; r < 4; ++r) {
            const int dd = d0 + brow0 + r * 4;
            const float* wr = wbase + (size_t)dd * TWOI;
            Bg[brow0 + r * 4][bcol] = wr[c0 + bcol];
            Bu[brow0 + r * 4][bcol] = wr[c0 + 512 + bcol];
        }
        __syncthreads();
#pragma unroll
        for (int kk = 0; kk < 16; ++kk) {
            const float4 a  = *reinterpret_cast<const float4*>(&As[kk][ty * 4]);
            const float4 bg = *reinterpret_cast<const float4*>(&Bg[kk][tx * 4]);
            const float4 bu = *reinterpret_cast<const float4*>(&Bu[kk][tx * 4]);
            const float aa[4] = { a.x, a.y, a.z, a.w };
            const float gg[4] = { bg.x, bg.y, bg.z, bg.w };
            const float uu[4] = { bu.x, bu.y, bu.z, bu.w };
#pragma unroll
            for (int i2 = 0; i2 < 4; ++i2)
#pragma unroll
                for (int j = 0; j < 4; ++j) {
                    accg[i2][j] += aa[i2] * gg[j];
                    accu[i2][j] += aa[i2] * uu[j];
                }
        }
        __syncthreads();
    }
#pragma unroll
    for (int i2 = 0; i2 < 4; ++i2) {
        const int r = ty * 4 + i2;
        const int gr = m0 + r;
        if (gr < nrows) {
            const int pv = perm[base + gr];
            const float wgt = sel_w[pv];
            float* hrow = h + (size_t)(base + gr) * I_DIM + c0;
#pragma unroll
            for (int j = 0; j < 4; ++j) {
                const float g = accg[i2][j];
                const float u = accu[i2][j];
                const float s = g / (1.f + expf(-g));
                hrow[tx * 4 + j] = s * u * wgt;
            }
        }
    }
}

__global__ __launch_bounds__(256) void down_gemm_kernel(
    const float* __restrict__ h, const float* __restrict__ wdn,
    const int* __restrict__ offsets, const int* __restrict__ perm,
    float* __restrict__ y)
{
    const int e = blockIdx.z;
    const int base = offsets[e];
    const int nrows = offsets[e + 1] - base;
    const int m0 = blockIdx.y * 64;
    if (m0 >= nrows) return;
    const int c0 = blockIdx.x * 64;
    const int tid = threadIdx.x;
    __shared__ float As[16][64];
    __shared__ float Bs[16][64];
    const int lrow = tid >> 2;
    const int c4 = (tid & 3) * 4;
    const int grow = m0 + lrow;
    const bool arow_ok = (grow < nrows);
    const float* hrow = arow_ok ? (h + (size_t)(base + grow) * I_DIM) : nullptr;
    const int bcol = tid & 63;
    const int brow0 = tid >> 6;
    const float* wbase = wdn + (size_t)e * I_DIM * D_DIM;
    const int tx = tid & 15, ty = tid >> 4;
    float acc[4][4] = {};
    for (int d0 = 0; d0 < I_DIM; d0 += 16) {
        float4 av = make_float4(0.f, 0.f, 0.f, 0.f);
        if (arow_ok) av = *reinterpret_cast<const float4*>(hrow + d0 + c4);
        As[c4 + 0][lrow] = av.x; As[c4 + 1][lrow] = av.y;
        As[c4 + 2][lrow] = av.z; As[c4 + 3][lrow] = av.w;
#pragma unroll
        for (int r = 0; r < 4; ++r) {
            const int dd = d0 + brow0 + r * 4;
            Bs[brow0 + r * 4][bcol] = wbase[(size_t)dd * D_DIM + c0 + bcol];
        }
        __syncthreads();
#pragma unroll
        for (int kk = 0; kk < 16; ++kk) {
            const float4 a = *reinterpret_cast<const float4*>(&As[kk][ty * 4]);
            const float4 b = *reinterpret_cast<const float4*>(&Bs[kk][tx * 4]);
            const float aa[4] = { a.x, a.y, a.z, a.w };
            const float bb[4] = { b.x, b.y, b.z, b.w };
#pragma unroll
            for (int i2 = 0; i2 < 4; ++i2)
#pragma unroll
                for (int j = 0; j < 4; ++j)
                    acc[i2][j] += aa[i2] * bb[j];
        }
        __syncthreads();
    }
#pragma unroll
    for (int i2 = 0; i2 < 4; ++i2) {
        const int r = ty * 4 + i2;
        const int gr = m0 + r;
        if (gr < nrows) {
            const int pv = perm[base + gr];
            const int t = pv >> 2;
            float* yrow = y + (size_t)t * D_DIM + c0;
#pragma unroll
            for (int j = 0; j < 4; ++j)
                atomicAdd(&yrow[tx * 4 + j], acc[i2][j]);
        }
    }
}

// ---------------- launch -----------------------------------------------------
extern "C" void kernel_launch(void* const* d_in, const int* in_sizes, int n_in,
                              void* d_out, int out_size, void* d_ws, size_t ws_size,
                              hipStream_t stream)
{
    const float* x      = (const float*)d_in[0];
    const float* router = (const float*)d_in[1];
    const float* rbias  = (const float*)d_in[2];
    const float* wgu    = (const float*)d_in[3];
    const float* wdn    = (const float*)d_in[4];
    float* out = (float*)d_out;

    char* ws = (char*)d_ws;
    int*   sel_idx = (int*)(ws);                    // 32 KB
    float* sel_w   = (float*)(ws + 32768);          // 32 KB
    int*   perm    = (int*)(ws + 65536);            // 32 KB
    int*   inv     = (int*)(ws + 98304);            // 32 KB
    int*   counts  = (int*)(ws + 131072);
    int*   offsets = (int*)(ws + 131328);
    int*   cursor  = (int*)(ws + 131584);
    __bf16* xb     = (__bf16*)(ws + 262144);        // 4 MB
    __bf16* hb     = (__bf16*)(ws + 4456448);       // 8 MB
    __bf16* wguT   = (__bf16*)(ws + 12845056);      // 32 MB
    __bf16* wdnT   = (__bf16*)(ws + 46399488);      // 16 MB -> 63176704
    float* yp      = (float*)(ws + 63242240);       // 32 MB -> 96796672
    float* hf      = (float*)(ws + 262144);         // fallback fp32 h (16.8 MB)

    const bool fast = (ws_size >= 96796672ULL);
    const bool mid  = (ws_size >= 63242240ULL);

    hipMemsetAsync(counts, 0, 64, stream);
    if (!fast)
        hipMemsetAsync(out, 0, (size_t)T_TOK * D_DIM * sizeof(float), stream);

    router_lds_kernel<<<T_TOK / RT_TOK, 256, 0, stream>>>(x, router, rbias, sel_idx, sel_w, counts);
    scan_stats_kernel<<<1, 64, 0, stream>>>(counts, offsets, cursor,
                                            out + (size_t)T_TOK * D_DIM);
    scatter_kernel<<<(T_TOK * K_TOP + 255) / 256, 256, 0, stream>>>(sel_idx, cursor, perm, inv);

    if (mid) {
        convert_x_kernel<<<T_TOK * D_DIM / 8 / 256, 256, 0, stream>>>(x, xb);
        transpose_w_kernel<<<dim3(TWOI / 32, D_DIM / 32, E_NUM), 256, 0, stream>>>(wgu, wguT, D_DIM, TWOI);
        transpose_w_kernel<<<dim3(D_DIM / 32, I_DIM / 32, E_NUM), 256, 0, stream>>>(wdn, wdnT, I_DIM, D_DIM);
        gate_mfma_kernel<<<dim3(16, 16, E_NUM), 256, 0, stream>>>(xb, wguT, offsets, perm, sel_w, hb);
        if (fast) {
            down_mfma_p_kernel<<<dim3(16, 16, E_NUM), 256, 0, stream>>>(hb, wdnT, offsets, yp);
            combine_kernel<<<T_TOK, 256, 0, stream>>>(yp, inv, out);
        } else {
            down_mfma_kernel<<<dim3(8, 16, E_NUM), 256, 0, stream>>>(hb, wdnT, offsets, perm, out);
        }
    } else {
        gate_gemm_kernel<<<dim3(8, 32, E_NUM), 256, 0, stream>>>(x, wgu, offsets, perm, sel_w, hf);
        down_gemm_kernel<<<dim3(16, 32, E_NUM), 256, 0, stream>>>(hf, wdn, offsets, perm, out);
    }
}